// Round 3
// baseline (65.836 us; speedup 1.0000x reference)
//
#include <hip/hip_runtime.h>
#include <math.h>

// Problem constants (match reference setup_inputs)
#define A_CNT   256
#define N_VIEW  20
#define D_DIM   256
#define NCLS    19
#define N_ROWS  (A_CNT * N_VIEW)   // 5120
#define N_TILES 160                // 8 anchor-tiles x 20 views, 32 rows each

#define TEMP      0.1
#define BASE_TEMP 0.07

// MFMA fragment types: 32x32x16 bf16 -> 8 bf16 in (4 VGPRs), 16 f32 accum
typedef short  s16x8  __attribute__((ext_vector_type(8)));
typedef float  f32x16 __attribute__((ext_vector_type(16)));

// ---------------------------------------------------------------------------
// One wave per tile: 32 anchors (one view) x 32 classes (19 real, rest pad).
//   D = A(proto) x B(feats^T) via v_mfma_f32_32x32x16_bf16, K=256 in 16 steps
//   A-frag: row(class) = lane&31, k = (lane>>5)*8 + e   [classes>18 -> class 0,
//           gated out later by cnt==0]
//   B-frag: col(anchor) = a0 + (lane&31), same k layout
//   C/D (m74/m101-verified): col = lane&31 = ANCHOR,
//           row = (reg&3) + 8*(reg>>2) + 4*(lane>>5) = CLASS
// => lane owns one anchor and 16 of the 32 class-logits; softmax over classes
//    is a 16-elem local reduce + one shfl_xor(32).
// All global loads (fragments + labels/btch) are issued before any use so the
// cold-cache latency (poison fill evicts L2/L3 every iter) is paid once.
// ---------------------------------------------------------------------------
__global__ __launch_bounds__(64) void pcl_fused(
        const unsigned short* __restrict__ feats,   // [A, N_VIEW, D] bf16 bits
        const unsigned short* __restrict__ proto,   // [NCLS, D] bf16 bits
        const int*   __restrict__ labels,           // [A]
        const int*   __restrict__ btch,             // [A]
        double* __restrict__ gsum,                  // ws: zeroed by memset
        int*    __restrict__ gcnt,                  // ws: zeroed by memset
        float*  __restrict__ out) {
    __shared__ int sCnt[32];      // per-class counts, zero-padded to 32
    __shared__ int sCb[40];       // per-(class,btch) counts

    const int l  = threadIdx.x;   // 0..63 (single wave)
    const int b  = blockIdx.x;    // 0..159
    const int v  = b >> 3;        // view
    const int a0 = (b & 7) << 5;  // first anchor of tile
    const int lo = l & 31;
    const int hs = l >> 5;        // k-half select

    // ---- zero LDS counters (no barrier needed before global loads) ----
    if (l < 32) sCnt[l] = 0;
    if (l < 40) sCb[l]  = 0;

    // ---- issue ALL global loads up front (one latency exposure) ----
    // B-frags: feats row (a0+lo, v), k = s*16 + hs*8
    const unsigned short* fbase =
        feats + ((size_t)((a0 + lo) * N_VIEW + v)) * D_DIM + hs * 8;
    s16x8 bf[16];
#pragma unroll
    for (int s = 0; s < 16; ++s)
        bf[s] = *(const s16x8*)(fbase + s * 16);

    // A-frags: proto class lo (clamped; pad classes read class 0, gated out)
    const int pc = (lo < NCLS) ? lo : 0;
    const unsigned short* pbase = proto + (size_t)pc * D_DIM + hs * 8;
    s16x8 af[16];
#pragma unroll
    for (int s = 0; s < 16; ++s)
        af[s] = *(const s16x8*)(pbase + s * 16);

    // prep: 4 anchors per lane, plus this lane's own anchor label/btch
    int labr[4], btr[4];
#pragma unroll
    for (int i = 0; i < 4; ++i) {
        labr[i] = labels[l + 64 * i];
        btr[i]  = btch[l + 64 * i];
    }
    const int aa = a0 + lo;        // this lane's anchor
    const int ca = labels[aa];
    const int ba = btch[aa];

    __syncthreads();               // zeros visible (cheap: single wave)
#pragma unroll
    for (int i = 0; i < 4; ++i) {
        atomicAdd(&sCnt[labr[i]], 1);
        atomicAdd(&sCb[labr[i] * 2 + btr[i]], 1);
    }

    // ---- 16 MFMAs, two 8-deep chains to halve dependency depth ----
    f32x16 accA = {0.f,0.f,0.f,0.f,0.f,0.f,0.f,0.f,
                   0.f,0.f,0.f,0.f,0.f,0.f,0.f,0.f};
    f32x16 accB = accA;
#pragma unroll
    for (int s = 0; s < 16; s += 2) {
        accA = __builtin_amdgcn_mfma_f32_32x32x16_bf16(af[s],     bf[s],     accA, 0, 0, 0);
        accB = __builtin_amdgcn_mfma_f32_32x32x16_bf16(af[s + 1], bf[s + 1], accB, 0, 0, 0);
    }

    __syncthreads();               // counts complete

    // ---- epilogue: lane owns anchor aa, classes (r&3)+8*(r>>2)+4*hs ----
    const float invT = (float)(1.0 / TEMP);
    float d[16];
    int   cn[16];
    float mloc = -__builtin_inff();
#pragma unroll
    for (int r = 0; r < 16; ++r) {
        const int c = (r & 3) + 8 * (r >> 2) + 4 * hs;
        d[r]  = (accA[r] + accB[r]) * invT;
        cn[r] = sCnt[c];           // 2-way broadcast LDS read
        if (cn[r] > 0) mloc = fmaxf(mloc, d[r]);
    }
    const float mx = fmaxf(mloc, __shfl_xor(mloc, 32, 64));

    float eloc = 0.f, dloc = 0.f;
#pragma unroll
    for (int r = 0; r < 16; ++r) {
        const int c = (r & 3) + 8 * (r >> 2) + 4 * hs;
        if (cn[r] > 0 && c != ca) eloc += (float)cn[r] * __expf(d[r] - mx);
        if (c == ca)              dloc += d[r];
    }
    const float e   = eloc + __shfl_xor(eloc, 32, 64);
    const float dca = dloc + __shfl_xor(dloc, 32, 64);

    const float S    = (float)N_VIEW * e;             // 20 * weighted neg sum
    const float md   = dca - mx;                      // <= 0
    const float lp   = md - __logf(__expf(md) + S);
    const float posN = (float)N_VIEW * (float)sCb[ca * 2 + (1 - ba)];
    const float mlp  = posN * lp / (posN + 1e-8f);

    // each anchor counted once (hs==0 half); butterfly wave reduce
    float val = (hs == 0) ? mlp : 0.f;
#pragma unroll
    for (int o = 1; o <= 32; o <<= 1) val += __shfl_xor(val, o, 64);

    if (l == 0) {
        atomicAdd(gsum, (double)val);
        __threadfence();
        const int old = atomicAdd(gcnt, 1);
        if (old == N_TILES - 1) {          // last block finalizes
            __threadfence();
            const double s    = atomicAdd(gsum, 0.0);   // read current total
            const double loss = -(TEMP / BASE_TEMP) * s / (double)N_ROWS;
            out[0] = isnan(loss) ? 0.0f : (float)loss;
        }
    }
}

extern "C" void kernel_launch(void* const* d_in, const int* in_sizes, int n_in,
                              void* d_out, int out_size, void* d_ws, size_t ws_size,
                              hipStream_t stream) {
    const unsigned short* feats  = (const unsigned short*)d_in[0]; // bf16 [256,20,256]
    const unsigned short* proto  = (const unsigned short*)d_in[1]; // bf16 [19,256]
    const int*            labels = (const int*)d_in[2];            // [256] i32
    const int*            btch   = (const int*)d_in[3];            // [256] i32
    float* out = (float*)d_out;                                    // f32 scalar

    double* gsum = (double*)d_ws;                // 8 B
    int*    gcnt = (int*)((char*)d_ws + 8);      // 4 B

    hipMemsetAsync(d_ws, 0, 16, stream);         // tiny graph-capturable node
    pcl_fused<<<N_TILES, 64, 0, stream>>>(feats, proto, labels, btch,
                                          gsum, gcnt, out);
}

// Round 4
// 62.031 us; speedup vs baseline: 1.0613x; 1.0613x over previous
//
#include <hip/hip_runtime.h>
#include <math.h>

// Problem constants (match reference setup_inputs)
#define A_CNT   256
#define N_VIEW  20
#define D_DIM   256
#define NCLS    19
#define N_ROWS  (A_CNT * N_VIEW)   // 5120
#define N_TILES 160                // 8 anchor-tiles x 20 views, 32 rows each

#define TEMP      0.1
#define BASE_TEMP 0.07

// MFMA fragment types: 32x32x16 bf16 -> 8 bf16 in (4 VGPRs), 16 f32 accum
typedef short  s16x8  __attribute__((ext_vector_type(8)));
typedef float  f32x16 __attribute__((ext_vector_type(16)));

// ---------------------------------------------------------------------------
// Kernel 1 — one wave per tile: 32 anchors (one view) x 32 classes (19 real).
//   D = A(proto) x B(feats^T) via v_mfma_f32_32x32x16_bf16, K=256 in 16 steps
//   A-frag: row(class) = lane&31, k = (lane>>5)*8 + e   [classes>18 -> class 0,
//           gated out later by cnt==0]
//   B-frag: col(anchor) = a0 + (lane&31), same k layout
//   C/D (m74/m101-verified): col = lane&31 = ANCHOR,
//           row = (reg&3) + 8*(reg>>2) + 4*(lane>>5) = CLASS
// => lane owns one anchor and 16 of the 32 class-logits; softmax over classes
//    is a 16-elem local reduce + one shfl_xor(32).
// NO global atomics / fences: block result goes out as a plain store to
// partial[blockIdx.x] (workspace needs no init), reduced by kernel 2.
// ---------------------------------------------------------------------------
__global__ __launch_bounds__(64) void pcl_main(
        const unsigned short* __restrict__ feats,   // [A, N_VIEW, D] bf16 bits
        const unsigned short* __restrict__ proto,   // [NCLS, D] bf16 bits
        const int*   __restrict__ labels,           // [A]
        const int*   __restrict__ btch,             // [A]
        double* __restrict__ partial) {             // [N_TILES] plain stores
    __shared__ int sCnt[32];      // per-class counts, zero-padded to 32
    __shared__ int sCb[40];       // per-(class,btch) counts

    const int l  = threadIdx.x;   // 0..63 (single wave)
    const int b  = blockIdx.x;    // 0..159
    const int v  = b >> 3;        // view
    const int a0 = (b & 7) << 5;  // first anchor of tile
    const int lo = l & 31;
    const int hs = l >> 5;        // k-half select

    // ---- zero LDS counters ----
    if (l < 32) sCnt[l] = 0;
    if (l < 40) sCb[l]  = 0;

    // ---- issue ALL global loads up front (one latency exposure) ----
    // B-frags: feats row (a0+lo, v), k = s*16 + hs*8
    const unsigned short* fbase =
        feats + ((size_t)((a0 + lo) * N_VIEW + v)) * D_DIM + hs * 8;
    s16x8 bf[16];
#pragma unroll
    for (int s = 0; s < 16; ++s)
        bf[s] = *(const s16x8*)(fbase + s * 16);

    // A-frags: proto class lo (clamped; pad classes read class 0, gated out)
    const int pc = (lo < NCLS) ? lo : 0;
    const unsigned short* pbase = proto + (size_t)pc * D_DIM + hs * 8;
    s16x8 af[16];
#pragma unroll
    for (int s = 0; s < 16; ++s)
        af[s] = *(const s16x8*)(pbase + s * 16);

    // prep: 4 anchors per lane, plus this lane's own anchor label/btch
    int labr[4], btr[4];
#pragma unroll
    for (int i = 0; i < 4; ++i) {
        labr[i] = labels[l + 64 * i];
        btr[i]  = btch[l + 64 * i];
    }
    const int aa = a0 + lo;        // this lane's anchor
    const int ca = labels[aa];
    const int ba = btch[aa];

    __syncthreads();               // zeros visible (single wave: trivial)
#pragma unroll
    for (int i = 0; i < 4; ++i) {
        atomicAdd(&sCnt[labr[i]], 1);
        atomicAdd(&sCb[labr[i] * 2 + btr[i]], 1);
    }

    // ---- 16 MFMAs, two 8-deep chains to halve dependency depth ----
    f32x16 accA = {0.f,0.f,0.f,0.f,0.f,0.f,0.f,0.f,
                   0.f,0.f,0.f,0.f,0.f,0.f,0.f,0.f};
    f32x16 accB = accA;
#pragma unroll
    for (int s = 0; s < 16; s += 2) {
        accA = __builtin_amdgcn_mfma_f32_32x32x16_bf16(af[s],     bf[s],     accA, 0, 0, 0);
        accB = __builtin_amdgcn_mfma_f32_32x32x16_bf16(af[s + 1], bf[s + 1], accB, 0, 0, 0);
    }

    __syncthreads();               // counts complete

    // ---- epilogue: lane owns anchor aa, classes (r&3)+8*(r>>2)+4*hs ----
    const float invT = (float)(1.0 / TEMP);
    float d[16];
    int   cn[16];
    float mloc = -__builtin_inff();
#pragma unroll
    for (int r = 0; r < 16; ++r) {
        const int c = (r & 3) + 8 * (r >> 2) + 4 * hs;
        d[r]  = (accA[r] + accB[r]) * invT;
        cn[r] = sCnt[c];           // 2-way broadcast LDS read
        if (cn[r] > 0) mloc = fmaxf(mloc, d[r]);
    }
    const float mx = fmaxf(mloc, __shfl_xor(mloc, 32, 64));

    float eloc = 0.f, dloc = 0.f;
#pragma unroll
    for (int r = 0; r < 16; ++r) {
        const int c = (r & 3) + 8 * (r >> 2) + 4 * hs;
        if (cn[r] > 0 && c != ca) eloc += (float)cn[r] * __expf(d[r] - mx);
        if (c == ca)              dloc += d[r];
    }
    const float e   = eloc + __shfl_xor(eloc, 32, 64);
    const float dca = dloc + __shfl_xor(dloc, 32, 64);

    const float S    = (float)N_VIEW * e;             // 20 * weighted neg sum
    const float md   = dca - mx;                      // <= 0
    const float lp   = md - __logf(__expf(md) + S);
    const float posN = (float)N_VIEW * (float)sCb[ca * 2 + (1 - ba)];
    const float mlp  = posN * lp / (posN + 1e-8f);

    // each anchor counted once (hs==0 half); butterfly wave reduce
    float val = (hs == 0) ? mlp : 0.f;
#pragma unroll
    for (int o = 1; o <= 32; o <<= 1) val += __shfl_xor(val, o, 64);

    if (l == 0) partial[b] = (double)val;   // plain store — no atomics, no fence
}

// ---------------------------------------------------------------------------
// Kernel 2 — single wave: reduce 160 partials, write the scalar loss.
// Stream order gives cross-dispatch visibility (runtime acquire/release).
// ---------------------------------------------------------------------------
__global__ __launch_bounds__(64) void pcl_fin(
        const double* __restrict__ partial,  // [N_TILES]
        float* __restrict__ out) {
    const int l = threadIdx.x;   // 0..63
    double s = partial[l] + partial[l + 64];       // 0..127
    if (l < N_TILES - 128) s += partial[l + 128];  // 128..159
#pragma unroll
    for (int o = 1; o <= 32; o <<= 1) s += __shfl_xor(s, o, 64);
    if (l == 0) {
        const double loss = -(TEMP / BASE_TEMP) * s / (double)N_ROWS;
        out[0] = isnan(loss) ? 0.0f : (float)loss;
    }
}

extern "C" void kernel_launch(void* const* d_in, const int* in_sizes, int n_in,
                              void* d_out, int out_size, void* d_ws, size_t ws_size,
                              hipStream_t stream) {
    const unsigned short* feats  = (const unsigned short*)d_in[0]; // bf16 [256,20,256]
    const unsigned short* proto  = (const unsigned short*)d_in[1]; // bf16 [19,256]
    const int*            labels = (const int*)d_in[2];            // [256] i32
    const int*            btch   = (const int*)d_in[3];            // [256] i32
    float* out = (float*)d_out;                                    // f32 scalar

    double* partial = (double*)d_ws;   // 160 * 8 B, plain stores (no init)

    pcl_main<<<N_TILES, 64, 0, stream>>>(feats, proto, labels, btch, partial);
    pcl_fin<<<1, 64, 0, stream>>>(partial, out);
}